// Round 18
// baseline (80.839 us; speedup 1.0000x reference)
//
#include <hip/hip_runtime.h>
#include <math.h>

#define NN 50000
#define NE 800000
#define KD 256      // 2*D
#define DD 128
#define ROWS 32
#define STR 264     // padded LDS row stride (bf16 elems)
#define NT ((NN + ROWS - 1) / ROWS)   // 1563

// SpMV privatization geometry
#define EC 64
#define NR 4
#define RNG 12500
#define QPC 3125
#define NPB 196     // nodes per block in fused finish phase (256*196 = 50176)

// workspace layout (floats)
#define S_OFF   0
#define P_OFF   50176
#define CNT_OFF (P_OFF + EC * NN)
#define WS_NEED ((size_t)(CNT_OFF + 16) * 4)

typedef __bf16 bf16x4 __attribute__((ext_vector_type(4)));
typedef __bf16 bf16x8 __attribute__((ext_vector_type(8)));
typedef float f32x4 __attribute__((ext_vector_type(4)));

// Stage 1 (MFMA): R14 body, but B-frags loaded DIRECTLY from f32 W1 (L2-hot) with
// 1-step prefetch + in-register bf16 convert — prep kernel eliminated.
// Also zeroes out + sync counters (block 0).
__global__ __launch_bounds__(256, 5) void stage1_kernel(
    const float* __restrict__ x, const float* __restrict__ W1,
    const float* __restrict__ b1, const float* __restrict__ W2,
    float* __restrict__ s, float* __restrict__ out, unsigned* __restrict__ cnt)
{
    __shared__ __align__(16) __bf16 xs[ROWS * STR];   // 16896 B
    __shared__ float sred[4][ROWS];

    const int tid  = threadIdx.x;
    const int lane = tid & 63;
    const int w    = tid >> 6;
    const int g    = lane >> 4;
    const int li   = lane & 15;
    const int m0   = blockIdx.x * ROWS;

    if (blockIdx.x == 0 && tid == 0) { out[0] = 0.f; cnt[0] = 0u; cnt[1] = 0u; }

    const f32x4* xv = (const f32x4*)x;

    // Stage x tile in 2 batches of 4 loads (16 live staging VGPRs)
    #pragma unroll
    for (int b = 0; b < 2; ++b) {
        f32x4 xr[4];
        #pragma unroll
        for (int i = 0; i < 4; ++i) {
            int c = tid + (b * 4 + i) * 256;
            int r = c >> 6, kq = c & 63;
            int rr = m0 + r; rr = rr < NN ? rr : NN - 1;
            xr[i] = xv[(size_t)rr * 64 + kq];
        }
        #pragma unroll
        for (int i = 0; i < 4; ++i) {
            int c = tid + (b * 4 + i) * 256;
            int r = c >> 6, kq = c & 63;
            bf16x4 h = { (__bf16)xr[i][0], (__bf16)xr[i][1], (__bf16)xr[i][2], (__bf16)xr[i][3] };
            *(bf16x4*)&xs[r * STR + kq * 4] = h;
        }
    }

    // Direct B bases: wave w owns d-rows d0 = 32w+li and d0+16 of W1.
    // Frag k-element j = W1[row][ks*32 + g*8 + j] — same bijection as the A-side.
    const int d0 = w * 32 + li;
    const float* wb0 = W1 + (size_t)d0 * KD + g * 8;
    const float* wb1 = W1 + (size_t)(d0 + 16) * KD + g * 8;
    f32x4 p0l = *(const f32x4*)(wb0), p0h = *(const f32x4*)(wb0 + 4);
    f32x4 p1l = *(const f32x4*)(wb1), p1h = *(const f32x4*)(wb1 + 4);

    const float b1v0 = b1[d0], b1v1 = b1[d0 + 16];
    const float w2v0 = W2[d0], w2v1 = W2[d0 + 16];

    __syncthreads();

    // K-loop: A from LDS, B streamed from W1 (prefetch ks+1 under ks's MFMAs).
    f32x4 acc[2][2] = {};
    #pragma unroll
    for (int ks = 0; ks < 8; ++ks) {
        f32x4 c0l = p0l, c0h = p0h, c1l = p1l, c1h = p1h;
        if (ks < 7) {
            p0l = *(const f32x4*)(wb0 + (ks + 1) * 32);
            p0h = *(const f32x4*)(wb0 + (ks + 1) * 32 + 4);
            p1l = *(const f32x4*)(wb1 + (ks + 1) * 32);
            p1h = *(const f32x4*)(wb1 + (ks + 1) * 32 + 4);
        }
        bf16x8 cb0 = { (__bf16)c0l[0], (__bf16)c0l[1], (__bf16)c0l[2], (__bf16)c0l[3],
                       (__bf16)c0h[0], (__bf16)c0h[1], (__bf16)c0h[2], (__bf16)c0h[3] };
        bf16x8 cb1 = { (__bf16)c1l[0], (__bf16)c1l[1], (__bf16)c1l[2], (__bf16)c1l[3],
                       (__bf16)c1h[0], (__bf16)c1h[1], (__bf16)c1h[2], (__bf16)c1h[3] };
        const int ko = ks * 32 + g * 8;
        bf16x8 a0 = *(const bf16x8*)&xs[li * STR + ko];
        bf16x8 a1 = *(const bf16x8*)&xs[(li + 16) * STR + ko];
        acc[0][0] = __builtin_amdgcn_mfma_f32_16x16x32_bf16(a0, cb0, acc[0][0], 0, 0, 0);
        acc[0][1] = __builtin_amdgcn_mfma_f32_16x16x32_bf16(a0, cb1, acc[0][1], 0, 0, 0);
        acc[1][0] = __builtin_amdgcn_mfma_f32_16x16x32_bf16(a1, cb0, acc[1][0], 0, 0, 0);
        acc[1][1] = __builtin_amdgcn_mfma_f32_16x16x32_bf16(a1, cb1, acc[1][1], 0, 0, 0);
    }

    // Epilogue: v = sin(acc+b1)*W2, reduce over d (C/D: col=lane&15, row=(lane>>4)*4+reg)
    #pragma unroll
    for (int mt = 0; mt < 2; ++mt) {
        #pragma unroll
        for (int r = 0; r < 4; ++r) {
            float v = __sinf(acc[mt][0][r] + b1v0) * w2v0
                    + __sinf(acc[mt][1][r] + b1v1) * w2v1;
            v += __shfl_xor(v, 1); v += __shfl_xor(v, 2);
            v += __shfl_xor(v, 4); v += __shfl_xor(v, 8);
            if (li == 0) sred[w][mt * 16 + g * 4 + r] = v;
        }
    }
    __syncthreads();
    if (tid < ROWS) {
        int m = m0 + tid;
        if (m < NN) s[m] = sred[0][tid] + sred[1][tid] + sred[2][tid] + sred[3][tid];
    }
}

// Fused Stage 2+3: 256 blocks x 1024 threads, 50 KB LDS (all co-resident: <=2 blocks/CU
// by waves, 256 blocks <= capacity). Phase A = LDS-privatized SpMV -> P.
// Grid sync (counter + fences, pattern validated R11). Phase B = finish + sqrt.
__global__ __launch_bounds__(1024, 1) void spmv_finish_kernel(
    const int* __restrict__ erow, const int* __restrict__ ecol,
    const float* __restrict__ ew, const float* __restrict__ s,
    float* __restrict__ P, const float* __restrict__ b2,
    float* __restrict__ out, unsigned* __restrict__ cnt)
{
    __shared__ float lt[RNG];
    const int tid  = threadIdx.x;
    const int bid  = blockIdx.x;
    const int ecid = bid & 63;
    const int nr   = bid >> 6;
    const int base = nr * RNG;

    // ---- Phase A: privatized SpMV ----
    for (int i = tid; i < RNG; i += 1024) lt[i] = 0.f;
    __syncthreads();

    const int4*   r4p = (const int4*)erow;
    const int4*   c4p = (const int4*)ecol;
    const float4* w4p = (const float4*)ew;
    for (int q = tid; q < QPC; q += 1024) {
        int i = ecid * QPC + q;
        int4   r4 = r4p[i];
        int4   c4 = c4p[i];
        float4 w4 = w4p[i];
        unsigned a;
        a = (unsigned)(r4.x - base); if (a < RNG) atomicAdd(&lt[a], w4.x * s[c4.x]);
        a = (unsigned)(r4.y - base); if (a < RNG) atomicAdd(&lt[a], w4.y * s[c4.y]);
        a = (unsigned)(r4.z - base); if (a < RNG) atomicAdd(&lt[a], w4.z * s[c4.z]);
        a = (unsigned)(r4.w - base); if (a < RNG) atomicAdd(&lt[a], w4.w * s[c4.w]);
    }
    __syncthreads();

    {
        float4*       dst = (float4*)(P + (size_t)ecid * NN + base);
        const float4* src = (const float4*)lt;
        for (int j = tid; j < RNG / 4; j += 1024) dst[j] = src[j];
    }

    // ---- Grid sync: release P, acquire for readers ----
    __syncthreads();
    if (tid == 0) {
        __threadfence();
        atomicAdd(&cnt[0], 1u);
        while (atomicAdd(&cnt[0], 0u) < (unsigned)(NR * EC)) __builtin_amdgcn_s_sleep(2);
        __threadfence();
    }
    __syncthreads();

    // ---- Phase B: finish. Block handles nodes [bid*NPB, bid*NPB+NPB).
    // Thread (ecq = tid>>8 in 0..3, nl = tid&255): sums 16 ec-slices (coalesced over nl).
    {
        const int ecq = tid >> 8;
        const int nl  = tid & 255;
        const int n   = bid * NPB + nl;
        float a = 0.f;
        if (nl < NPB && n < NN) {
            #pragma unroll
            for (int j = 0; j < 16; ++j)
                a += P[(size_t)(ecq * 16 + j) * NN + n];
        }
        lt[ecq * 256 + nl] = a;   // lt safe to reuse: all P writes fenced+synced
        __syncthreads();

        float v = 0.f;
        if (tid < 256) {
            int n2 = bid * NPB + tid;
            if (tid < NPB && n2 < NN) {
                float t = lt[tid] + lt[256 + tid] + lt[512 + tid] + lt[768 + tid];
                float o = __sinf(t + b2[0]);
                v = o * o;
            }
        }
        #pragma unroll
        for (int off = 32; off; off >>= 1) v += __shfl_xor(v, off);
        if (tid < 256 && (tid & 63) == 0) lt[1024 + (tid >> 6)] = v;
        __syncthreads();
        if (tid == 0) {
            float tot = lt[1024] + lt[1025] + lt[1026] + lt[1027];
            atomicAdd(out, tot);
            __threadfence();
            unsigned old = atomicAdd(&cnt[1], 1u);
            if (old == (unsigned)(NR * EC - 1))
                out[0] = sqrtf(atomicAdd(out, 0.f));
        }
    }
}

// ---- Fallback path (small workspace): dense atomic SpMV ----
__global__ void spmv_fallback_kernel(const int* __restrict__ erow, const int* __restrict__ ecol,
                                     const float* __restrict__ ew, const float* __restrict__ s,
                                     float* __restrict__ t)
{
    int i = blockIdx.x * 256 + threadIdx.x;
    if (i >= NE / 4) return;
    int4   r4 = ((const int4*)erow)[i];
    int4   c4 = ((const int4*)ecol)[i];
    float4 w4 = ((const float4*)ew)[i];
    atomicAdd(&t[r4.x], w4.x * s[c4.x]);
    atomicAdd(&t[r4.y], w4.y * s[c4.y]);
    atomicAdd(&t[r4.z], w4.z * s[c4.z]);
    atomicAdd(&t[r4.w], w4.w * s[c4.w]);
}

__global__ void finish_fallback_kernel(const float* __restrict__ t, const float* __restrict__ b2,
                                       float* __restrict__ out)
{
    int n = blockIdx.x * 256 + threadIdx.x;
    float v = 0.f;
    if (n < NN) { float o = __sinf(t[n] + b2[0]); v = o * o; }
    #pragma unroll
    for (int off = 32; off; off >>= 1) v += __shfl_xor(v, off);
    __shared__ float partial[4];
    if ((threadIdx.x & 63) == 0) partial[threadIdx.x >> 6] = v;
    __syncthreads();
    if (threadIdx.x == 0)
        atomicAdd(out, partial[0] + partial[1] + partial[2] + partial[3]);
}

__global__ void sqrt_kernel(float* out) { out[0] = sqrtf(out[0]); }

__global__ void zero_kernel(float* t, float* out)
{
    int i = blockIdx.x * 256 + threadIdx.x;
    if (i < NN) t[i] = 0.f;
    if (i == 0) out[0] = 0.f;
}

extern "C" void kernel_launch(void* const* d_in, const int* in_sizes, int n_in,
                              void* d_out, int out_size, void* d_ws, size_t ws_size,
                              hipStream_t stream)
{
    const float* x   = (const float*)d_in[0];
    const float* W1  = (const float*)d_in[1];
    const float* b1  = (const float*)d_in[2];
    const float* W2  = (const float*)d_in[3];
    const float* b2  = (const float*)d_in[4];
    const int*   er  = (const int*)d_in[5];
    const int*   ec  = ((const int*)d_in[5]) + NE;
    const float* ew  = (const float*)d_in[6];
    float* out = (float*)d_out;

    float*    ws    = (float*)d_ws;
    float*    s_buf = ws + S_OFF;
    float*    P     = ws + P_OFF;
    unsigned* cnt   = (unsigned*)(ws + CNT_OFF);

    if (ws_size >= WS_NEED) {
        stage1_kernel<<<NT, 256, 0, stream>>>(x, W1, b1, W2, s_buf, out, cnt);
        spmv_finish_kernel<<<NR * EC, 1024, 0, stream>>>(er, ec, ew, s_buf, P, b2, out, cnt);
    } else {
        // Dense-atomic fallback (needs ~400 KB of ws)
        float* t = ws + P_OFF;
        zero_kernel<<<(NN + 255) / 256, 256, 0, stream>>>(t, out);
        stage1_kernel<<<NT, 256, 0, stream>>>(x, W1, b1, W2, s_buf, out, cnt);
        spmv_fallback_kernel<<<(NE / 4 + 255) / 256, 256, 0, stream>>>(er, ec, ew, s_buf, t);
        finish_fallback_kernel<<<(NN + 255) / 256, 256, 0, stream>>>(t, b2, out);
        sqrt_kernel<<<1, 1, 0, stream>>>(out);
    }
}

// Round 19
// 54.516 us; speedup vs baseline: 1.4828x; 1.4828x over previous
//
#include <hip/hip_runtime.h>
#include <math.h>

#define NN 50000
#define NE 800000
#define KD 256      // 2*D
#define DD 128
#define ROWS 32
#define STR 264     // padded LDS row stride (bf16 elems)
#define NT ((NN + ROWS - 1) / ROWS)   // 1563

// SpMV privatization geometry
#define EC 64
#define NR 4
#define RNG 12500
#define QPC 3125

// workspace layout (floats)
#define S_OFF   0
#define P_OFF   50176
#define CNT_OFF (P_OFF + EC * NN)
#define WS_NEED ((size_t)(CNT_OFF + 16) * 4)

typedef __bf16 bf16x4 __attribute__((ext_vector_type(4)));
typedef __bf16 bf16x8 __attribute__((ext_vector_type(8)));
typedef float f32x4 __attribute__((ext_vector_type(4)));

// Stage 1 (MFMA, prep-free — R18-validated body): B-frags loaded DIRECTLY from f32 W1
// (L2-hot) with 1-step prefetch + in-register bf16 convert. Zeroes out + counter.
__global__ __launch_bounds__(256, 5) void stage1_kernel(
    const float* __restrict__ x, const float* __restrict__ W1,
    const float* __restrict__ b1, const float* __restrict__ W2,
    float* __restrict__ s, float* __restrict__ out, unsigned* __restrict__ cnt)
{
    __shared__ __align__(16) __bf16 xs[ROWS * STR];   // 16896 B
    __shared__ float sred[4][ROWS];

    const int tid  = threadIdx.x;
    const int lane = tid & 63;
    const int w    = tid >> 6;
    const int g    = lane >> 4;
    const int li   = lane & 15;
    const int m0   = blockIdx.x * ROWS;

    if (blockIdx.x == 0 && tid == 0) { out[0] = 0.f; cnt[0] = 0u; }

    const f32x4* xv = (const f32x4*)x;

    // Stage x tile in 2 batches of 4 loads (16 live staging VGPRs)
    #pragma unroll
    for (int b = 0; b < 2; ++b) {
        f32x4 xr[4];
        #pragma unroll
        for (int i = 0; i < 4; ++i) {
            int c = tid + (b * 4 + i) * 256;
            int r = c >> 6, kq = c & 63;
            int rr = m0 + r; rr = rr < NN ? rr : NN - 1;
            xr[i] = xv[(size_t)rr * 64 + kq];
        }
        #pragma unroll
        for (int i = 0; i < 4; ++i) {
            int c = tid + (b * 4 + i) * 256;
            int r = c >> 6, kq = c & 63;
            bf16x4 h = { (__bf16)xr[i][0], (__bf16)xr[i][1], (__bf16)xr[i][2], (__bf16)xr[i][3] };
            *(bf16x4*)&xs[r * STR + kq * 4] = h;
        }
    }

    // Direct B bases: wave w owns d-rows d0 = 32w+li and d0+16 of W1.
    // Frag k-element j = W1[row][ks*32 + g*8 + j] — same bijection as the A-side.
    const int d0 = w * 32 + li;
    const float* wb0 = W1 + (size_t)d0 * KD + g * 8;
    const float* wb1 = W1 + (size_t)(d0 + 16) * KD + g * 8;
    f32x4 p0l = *(const f32x4*)(wb0), p0h = *(const f32x4*)(wb0 + 4);
    f32x4 p1l = *(const f32x4*)(wb1), p1h = *(const f32x4*)(wb1 + 4);

    const float b1v0 = b1[d0], b1v1 = b1[d0 + 16];
    const float w2v0 = W2[d0], w2v1 = W2[d0 + 16];

    __syncthreads();

    // K-loop: A from LDS, B streamed from W1 (prefetch ks+1 under ks's MFMAs).
    f32x4 acc[2][2] = {};
    #pragma unroll
    for (int ks = 0; ks < 8; ++ks) {
        f32x4 c0l = p0l, c0h = p0h, c1l = p1l, c1h = p1h;
        if (ks < 7) {
            p0l = *(const f32x4*)(wb0 + (ks + 1) * 32);
            p0h = *(const f32x4*)(wb0 + (ks + 1) * 32 + 4);
            p1l = *(const f32x4*)(wb1 + (ks + 1) * 32);
            p1h = *(const f32x4*)(wb1 + (ks + 1) * 32 + 4);
        }
        bf16x8 cb0 = { (__bf16)c0l[0], (__bf16)c0l[1], (__bf16)c0l[2], (__bf16)c0l[3],
                       (__bf16)c0h[0], (__bf16)c0h[1], (__bf16)c0h[2], (__bf16)c0h[3] };
        bf16x8 cb1 = { (__bf16)c1l[0], (__bf16)c1l[1], (__bf16)c1l[2], (__bf16)c1l[3],
                       (__bf16)c1h[0], (__bf16)c1h[1], (__bf16)c1h[2], (__bf16)c1h[3] };
        const int ko = ks * 32 + g * 8;
        bf16x8 a0 = *(const bf16x8*)&xs[li * STR + ko];
        bf16x8 a1 = *(const bf16x8*)&xs[(li + 16) * STR + ko];
        acc[0][0] = __builtin_amdgcn_mfma_f32_16x16x32_bf16(a0, cb0, acc[0][0], 0, 0, 0);
        acc[0][1] = __builtin_amdgcn_mfma_f32_16x16x32_bf16(a0, cb1, acc[0][1], 0, 0, 0);
        acc[1][0] = __builtin_amdgcn_mfma_f32_16x16x32_bf16(a1, cb0, acc[1][0], 0, 0, 0);
        acc[1][1] = __builtin_amdgcn_mfma_f32_16x16x32_bf16(a1, cb1, acc[1][1], 0, 0, 0);
    }

    // Epilogue: v = sin(acc+b1)*W2, reduce over d (C/D: col=lane&15, row=(lane>>4)*4+reg)
    #pragma unroll
    for (int mt = 0; mt < 2; ++mt) {
        #pragma unroll
        for (int r = 0; r < 4; ++r) {
            float v = __sinf(acc[mt][0][r] + b1v0) * w2v0
                    + __sinf(acc[mt][1][r] + b1v1) * w2v1;
            v += __shfl_xor(v, 1); v += __shfl_xor(v, 2);
            v += __shfl_xor(v, 4); v += __shfl_xor(v, 8);
            if (li == 0) sred[w][mt * 16 + g * 4 + r] = v;
        }
    }
    __syncthreads();
    if (tid < ROWS) {
        int m = m0 + tid;
        if (m < NN) s[m] = sred[0][tid] + sred[1][tid] + sred[2][tid] + sred[3][tid];
    }
}

// Stage 2 (LDS-privatized, R14 body): block (nr, ecid) scans chunk ecid, accumulates
// its node range in LDS, writes partial range to P[ecid][...]. (~8 us, measured R16.)
__global__ __launch_bounds__(1024, 1) void spmv_lds_kernel(
    const int* __restrict__ erow, const int* __restrict__ ecol,
    const float* __restrict__ ew, const float* __restrict__ s,
    float* __restrict__ P)
{
    __shared__ float lt[RNG];
    const int tid  = threadIdx.x;
    const int ecid = blockIdx.x & 63;
    const int nr   = blockIdx.x >> 6;
    const int base = nr * RNG;

    for (int i = tid; i < RNG; i += 1024) lt[i] = 0.f;
    __syncthreads();

    const int4*   r4p = (const int4*)erow;
    const int4*   c4p = (const int4*)ecol;
    const float4* w4p = (const float4*)ew;
    for (int q = tid; q < QPC; q += 1024) {
        int i = ecid * QPC + q;
        int4   r4 = r4p[i];
        int4   c4 = c4p[i];
        float4 w4 = w4p[i];
        unsigned a;
        a = (unsigned)(r4.x - base); if (a < RNG) atomicAdd(&lt[a], w4.x * s[c4.x]);
        a = (unsigned)(r4.y - base); if (a < RNG) atomicAdd(&lt[a], w4.y * s[c4.y]);
        a = (unsigned)(r4.z - base); if (a < RNG) atomicAdd(&lt[a], w4.z * s[c4.z]);
        a = (unsigned)(r4.w - base); if (a < RNG) atomicAdd(&lt[a], w4.w * s[c4.w]);
    }
    __syncthreads();

    float4*       dst = (float4*)(P + (size_t)ecid * NN + base);
    const float4* src = (const float4*)lt;
    for (int j = tid; j < RNG / 4; j += 1024) dst[j] = src[j];
}

// Stage 3 (R14 body): out += sum_n sin(sum_ec P[ec][n] + b2)^2 ; last block sqrt.
__global__ void finish_lds_kernel(const float* __restrict__ P, const float* __restrict__ b2,
                                  float* __restrict__ out, unsigned* __restrict__ counter,
                                  int nblocks)
{
    int n = blockIdx.x * 256 + threadIdx.x;
    float v = 0.f;
    if (n < NN) {
        float a = 0.f;
        #pragma unroll 8
        for (int ec = 0; ec < EC; ++ec) a += P[(size_t)ec * NN + n];
        float o = __sinf(a + b2[0]);
        v = o * o;
    }
    #pragma unroll
    for (int off = 32; off; off >>= 1) v += __shfl_xor(v, off);
    __shared__ float partial[4];
    if ((threadIdx.x & 63) == 0) partial[threadIdx.x >> 6] = v;
    __syncthreads();
    if (threadIdx.x == 0) {
        atomicAdd(out, partial[0] + partial[1] + partial[2] + partial[3]);
        __threadfence();
        unsigned old = atomicAdd(counter, 1u);
        if (old == (unsigned)(nblocks - 1)) {
            float tot = atomicAdd(out, 0.f);   // atomic read: all prior adds visible
            out[0] = sqrtf(tot);
        }
    }
}

// ---- Fallback path (small workspace): dense atomic SpMV ----
__global__ void spmv_fallback_kernel(const int* __restrict__ erow, const int* __restrict__ ecol,
                                     const float* __restrict__ ew, const float* __restrict__ s,
                                     float* __restrict__ t)
{
    int i = blockIdx.x * 256 + threadIdx.x;
    if (i >= NE / 4) return;
    int4   r4 = ((const int4*)erow)[i];
    int4   c4 = ((const int4*)ecol)[i];
    float4 w4 = ((const float4*)ew)[i];
    atomicAdd(&t[r4.x], w4.x * s[c4.x]);
    atomicAdd(&t[r4.y], w4.y * s[c4.y]);
    atomicAdd(&t[r4.z], w4.z * s[c4.z]);
    atomicAdd(&t[r4.w], w4.w * s[c4.w]);
}

__global__ void finish_fallback_kernel(const float* __restrict__ t, const float* __restrict__ b2,
                                       float* __restrict__ out)
{
    int n = blockIdx.x * 256 + threadIdx.x;
    float v = 0.f;
    if (n < NN) { float o = __sinf(t[n] + b2[0]); v = o * o; }
    #pragma unroll
    for (int off = 32; off; off >>= 1) v += __shfl_xor(v, off);
    __shared__ float partial[4];
    if ((threadIdx.x & 63) == 0) partial[threadIdx.x >> 6] = v;
    __syncthreads();
    if (threadIdx.x == 0)
        atomicAdd(out, partial[0] + partial[1] + partial[2] + partial[3]);
}

__global__ void sqrt_kernel(float* out) { out[0] = sqrtf(out[0]); }

__global__ void zero_kernel(float* t, float* out)
{
    int i = blockIdx.x * 256 + threadIdx.x;
    if (i < NN) t[i] = 0.f;
    if (i == 0) out[0] = 0.f;
}

extern "C" void kernel_launch(void* const* d_in, const int* in_sizes, int n_in,
                              void* d_out, int out_size, void* d_ws, size_t ws_size,
                              hipStream_t stream)
{
    const float* x   = (const float*)d_in[0];
    const float* W1  = (const float*)d_in[1];
    const float* b1  = (const float*)d_in[2];
    const float* W2  = (const float*)d_in[3];
    const float* b2  = (const float*)d_in[4];
    const int*   er  = (const int*)d_in[5];
    const int*   ec  = ((const int*)d_in[5]) + NE;
    const float* ew  = (const float*)d_in[6];
    float* out = (float*)d_out;

    float*    ws    = (float*)d_ws;
    float*    s_buf = ws + S_OFF;
    float*    P     = ws + P_OFF;
    unsigned* cnt   = (unsigned*)(ws + CNT_OFF);

    if (ws_size >= WS_NEED) {
        stage1_kernel<<<NT, 256, 0, stream>>>(x, W1, b1, W2, s_buf, out, cnt);
        spmv_lds_kernel<<<NR * EC, 1024, 0, stream>>>(er, ec, ew, s_buf, P);
        int fb = (NN + 255) / 256;
        finish_lds_kernel<<<fb, 256, 0, stream>>>(P, b2, out, cnt, fb);
    } else {
        // Dense-atomic fallback (needs ~400 KB of ws)
        float* t = ws + P_OFF;
        zero_kernel<<<(NN + 255) / 256, 256, 0, stream>>>(t, out);
        stage1_kernel<<<NT, 256, 0, stream>>>(x, W1, b1, W2, s_buf, out, cnt);
        spmv_fallback_kernel<<<(NE / 4 + 255) / 256, 256, 0, stream>>>(er, ec, ew, s_buf, t);
        finish_fallback_kernel<<<(NN + 255) / 256, 256, 0, stream>>>(t, b2, out);
        sqrt_kernel<<<1, 1, 0, stream>>>(out);
    }
}

// Round 20
// 41.074 us; speedup vs baseline: 1.9681x; 1.3273x over previous
//
#include <hip/hip_runtime.h>
#include <math.h>

#define NN 50000
#define NE 800000
#define KD 256      // 2*D
#define DD 128
#define ROWS 32
#define STR 264     // padded LDS row stride (bf16 elems)
#define NT ((NN + ROWS - 1) / ROWS)   // 1563

// SpMV privatization geometry
#define EC 64
#define NR 4
#define RNG 12500
#define QPC 3125

// workspace layout (floats)
#define S_OFF   0
#define P_OFF   50176
#define CNT_OFF (P_OFF + EC * NN)
#define W1P_OFF (CNT_OFF + 16)
#define WS_NEED ((size_t)(W1P_OFF + DD * KD / 2 + 16) * 4)

typedef __bf16 bf16x4 __attribute__((ext_vector_type(4)));
typedef __bf16 bf16x8 __attribute__((ext_vector_type(8)));
typedef float f32x4 __attribute__((ext_vector_type(4)));

// Prep: W1 f32 [128][256] -> FRAGMENT-MAJOR bf16; also zero out/counter.
__global__ void prep_w1_kernel(const float* __restrict__ W1, __bf16* __restrict__ W1p,
                               float* __restrict__ out, unsigned* __restrict__ counter)
{
    int i = blockIdx.x * 256 + threadIdx.x;   // one per (d, ks, g): 128*8*4 = 4096
    if (i == 0) { out[0] = 0.f; counter[0] = 0u; }
    if (i >= DD * 8 * 4) return;
    int g  = i & 3;
    int ks = (i >> 2) & 7;
    int d  = i >> 5;
    int dt = d >> 4, li = d & 15;
    const float* src = W1 + d * KD + ks * 32 + g * 8;
    float4 v0 = *(const float4*)(src);
    float4 v1 = *(const float4*)(src + 4);
    bf16x8 h = { (__bf16)v0.x, (__bf16)v0.y, (__bf16)v0.z, (__bf16)v0.w,
                 (__bf16)v1.x, (__bf16)v1.y, (__bf16)v1.z, (__bf16)v1.w };
    *(bf16x8*)&W1p[(size_t)(((dt * 8 + ks) * 64) + g * 16 + li) * 8] = h;
}

// Stage 1 (MFMA): EXACT R14 body except s stored as bf16 (halves spmv gather footprint).
__global__ __launch_bounds__(256, 6) void stage1_kernel(
    const float* __restrict__ x, const __bf16* __restrict__ W1p,
    const float* __restrict__ b1, const float* __restrict__ W2,
    __bf16* __restrict__ s, float* __restrict__ out, unsigned* __restrict__ counter)
{
    __shared__ __align__(16) __bf16 xs[ROWS * STR];   // 16896 B
    __shared__ float sred[4][ROWS];

    const int tid  = threadIdx.x;
    const int lane = tid & 63;
    const int w    = tid >> 6;
    const int g    = lane >> 4;
    const int li   = lane & 15;
    const int m0   = blockIdx.x * ROWS;

    if (blockIdx.x == 0 && tid == 0) { out[0] = 0.f; counter[0] = 0u; }

    const f32x4* xv = (const f32x4*)x;

    // Stage x tile in 2 batches of 4 loads (16 live staging VGPRs)
    #pragma unroll
    for (int b = 0; b < 2; ++b) {
        f32x4 xr[4];
        #pragma unroll
        for (int i = 0; i < 4; ++i) {
            int c = tid + (b * 4 + i) * 256;
            int r = c >> 6, kq = c & 63;
            int rr = m0 + r; rr = rr < NN ? rr : NN - 1;
            xr[i] = xv[(size_t)rr * 64 + kq];
        }
        #pragma unroll
        for (int i = 0; i < 4; ++i) {
            int c = tid + (b * 4 + i) * 256;
            int r = c >> 6, kq = c & 63;
            bf16x4 h = { (__bf16)xr[i][0], (__bf16)xr[i][1], (__bf16)xr[i][2], (__bf16)xr[i][3] };
            *(bf16x4*)&xs[r * STR + kq * 4] = h;
        }
    }

    // Frag-major B bases: wave w owns d-tiles 2w, 2w+1. Prefetch ks=0.
    const __bf16* fb0 = W1p + ((size_t)((2 * w)     * 8) * 64 + lane) * 8;
    const __bf16* fb1 = W1p + ((size_t)((2 * w + 1) * 8) * 64 + lane) * 8;
    bf16x8 nb0 = *(const bf16x8*)(fb0);
    bf16x8 nb1 = *(const bf16x8*)(fb1);

    const int d0 = w * 32 + li;
    const float b1v0 = b1[d0], b1v1 = b1[d0 + 16];
    const float w2v0 = W2[d0], w2v1 = W2[d0 + 16];

    __syncthreads();

    // K-loop: A from LDS, B streamed (prefetch ks+1 under ks's MFMAs).
    f32x4 acc[2][2] = {};
    #pragma unroll
    for (int ks = 0; ks < 8; ++ks) {
        bf16x8 cb0 = nb0, cb1 = nb1;
        if (ks < 7) {
            nb0 = *(const bf16x8*)(fb0 + (size_t)(ks + 1) * 512);
            nb1 = *(const bf16x8*)(fb1 + (size_t)(ks + 1) * 512);
        }
        const int ko = ks * 32 + g * 8;
        bf16x8 a0 = *(const bf16x8*)&xs[li * STR + ko];
        bf16x8 a1 = *(const bf16x8*)&xs[(li + 16) * STR + ko];
        acc[0][0] = __builtin_amdgcn_mfma_f32_16x16x32_bf16(a0, cb0, acc[0][0], 0, 0, 0);
        acc[0][1] = __builtin_amdgcn_mfma_f32_16x16x32_bf16(a0, cb1, acc[0][1], 0, 0, 0);
        acc[1][0] = __builtin_amdgcn_mfma_f32_16x16x32_bf16(a1, cb0, acc[1][0], 0, 0, 0);
        acc[1][1] = __builtin_amdgcn_mfma_f32_16x16x32_bf16(a1, cb1, acc[1][1], 0, 0, 0);
    }

    // Epilogue: v = sin(acc+b1)*W2, reduce over d (C/D: col=lane&15, row=(lane>>4)*4+reg)
    #pragma unroll
    for (int mt = 0; mt < 2; ++mt) {
        #pragma unroll
        for (int r = 0; r < 4; ++r) {
            float v = __sinf(acc[mt][0][r] + b1v0) * w2v0
                    + __sinf(acc[mt][1][r] + b1v1) * w2v1;
            v += __shfl_xor(v, 1); v += __shfl_xor(v, 2);
            v += __shfl_xor(v, 4); v += __shfl_xor(v, 8);
            if (li == 0) sred[w][mt * 16 + g * 4 + r] = v;
        }
    }
    __syncthreads();
    if (tid < ROWS) {
        int m = m0 + tid;
        if (m < NN)
            s[m] = (__bf16)(sred[0][tid] + sred[1][tid] + sred[2][tid] + sred[3][tid]);
    }
}

// Stage 2 (LDS-privatized, R14 body; s gathers now bf16 — 100 KB footprint, L1-friendlier).
__global__ __launch_bounds__(1024, 1) void spmv_lds_kernel(
    const int* __restrict__ erow, const int* __restrict__ ecol,
    const float* __restrict__ ew, const __bf16* __restrict__ s,
    float* __restrict__ P)
{
    __shared__ float lt[RNG];
    const int tid  = threadIdx.x;
    const int ecid = blockIdx.x & 63;
    const int nr   = blockIdx.x >> 6;
    const int base = nr * RNG;

    for (int i = tid; i < RNG; i += 1024) lt[i] = 0.f;
    __syncthreads();

    const int4*   r4p = (const int4*)erow;
    const int4*   c4p = (const int4*)ecol;
    const float4* w4p = (const float4*)ew;
    for (int q = tid; q < QPC; q += 1024) {
        int i = ecid * QPC + q;
        int4   r4 = r4p[i];
        int4   c4 = c4p[i];
        float4 w4 = w4p[i];
        unsigned a;
        a = (unsigned)(r4.x - base); if (a < RNG) atomicAdd(&lt[a], w4.x * (float)s[c4.x]);
        a = (unsigned)(r4.y - base); if (a < RNG) atomicAdd(&lt[a], w4.y * (float)s[c4.y]);
        a = (unsigned)(r4.z - base); if (a < RNG) atomicAdd(&lt[a], w4.z * (float)s[c4.z]);
        a = (unsigned)(r4.w - base); if (a < RNG) atomicAdd(&lt[a], w4.w * (float)s[c4.w]);
    }
    __syncthreads();

    float4*       dst = (float4*)(P + (size_t)ecid * NN + base);
    const float4* src = (const float4*)lt;
    for (int j = tid; j < RNG / 4; j += 1024) dst[j] = src[j];
}

// Stage 3 (R14 body): out += sum_n sin(sum_ec P[ec][n] + b2)^2 ; last block sqrt.
__global__ void finish_lds_kernel(const float* __restrict__ P, const float* __restrict__ b2,
                                  float* __restrict__ out, unsigned* __restrict__ counter,
                                  int nblocks)
{
    int n = blockIdx.x * 256 + threadIdx.x;
    float v = 0.f;
    if (n < NN) {
        float a = 0.f;
        #pragma unroll 8
        for (int ec = 0; ec < EC; ++ec) a += P[(size_t)ec * NN + n];
        float o = __sinf(a + b2[0]);
        v = o * o;
    }
    #pragma unroll
    for (int off = 32; off; off >>= 1) v += __shfl_xor(v, off);
    __shared__ float partial[4];
    if ((threadIdx.x & 63) == 0) partial[threadIdx.x >> 6] = v;
    __syncthreads();
    if (threadIdx.x == 0) {
        atomicAdd(out, partial[0] + partial[1] + partial[2] + partial[3]);
        __threadfence();
        unsigned old = atomicAdd(counter, 1u);
        if (old == (unsigned)(nblocks - 1)) {
            float tot = atomicAdd(out, 0.f);   // atomic read: all prior adds visible
            out[0] = sqrtf(tot);
        }
    }
}

// ---- Fallback path (small workspace): dense atomic SpMV ----
__global__ void spmv_fallback_kernel(const int* __restrict__ erow, const int* __restrict__ ecol,
                                     const float* __restrict__ ew, const __bf16* __restrict__ s,
                                     float* __restrict__ t)
{
    int i = blockIdx.x * 256 + threadIdx.x;
    if (i >= NE / 4) return;
    int4   r4 = ((const int4*)erow)[i];
    int4   c4 = ((const int4*)ecol)[i];
    float4 w4 = ((const float4*)ew)[i];
    atomicAdd(&t[r4.x], w4.x * (float)s[c4.x]);
    atomicAdd(&t[r4.y], w4.y * (float)s[c4.y]);
    atomicAdd(&t[r4.z], w4.z * (float)s[c4.z]);
    atomicAdd(&t[r4.w], w4.w * (float)s[c4.w]);
}

__global__ void finish_fallback_kernel(const float* __restrict__ t, const float* __restrict__ b2,
                                       float* __restrict__ out)
{
    int n = blockIdx.x * 256 + threadIdx.x;
    float v = 0.f;
    if (n < NN) { float o = __sinf(t[n] + b2[0]); v = o * o; }
    #pragma unroll
    for (int off = 32; off; off >>= 1) v += __shfl_xor(v, off);
    __shared__ float partial[4];
    if ((threadIdx.x & 63) == 0) partial[threadIdx.x >> 6] = v;
    __syncthreads();
    if (threadIdx.x == 0)
        atomicAdd(out, partial[0] + partial[1] + partial[2] + partial[3]);
}

__global__ void sqrt_kernel(float* out) { out[0] = sqrtf(out[0]); }

__global__ void zero_kernel(float* t, float* out)
{
    int i = blockIdx.x * 256 + threadIdx.x;
    if (i < NN) t[i] = 0.f;
    if (i == 0) out[0] = 0.f;
}

extern "C" void kernel_launch(void* const* d_in, const int* in_sizes, int n_in,
                              void* d_out, int out_size, void* d_ws, size_t ws_size,
                              hipStream_t stream)
{
    const float* x   = (const float*)d_in[0];
    const float* W1  = (const float*)d_in[1];
    const float* b1  = (const float*)d_in[2];
    const float* W2  = (const float*)d_in[3];
    const float* b2  = (const float*)d_in[4];
    const int*   er  = (const int*)d_in[5];
    const int*   ec  = ((const int*)d_in[5]) + NE;
    const float* ew  = (const float*)d_in[6];
    float* out = (float*)d_out;

    float*    ws    = (float*)d_ws;
    __bf16*   s_buf = (__bf16*)(ws + S_OFF);     // 100 KB (fits the old 50176-float slot)
    float*    P     = ws + P_OFF;
    unsigned* cnt   = (unsigned*)(ws + CNT_OFF);
    __bf16*   W1p   = (__bf16*)(ws + W1P_OFF);

    if (ws_size >= WS_NEED) {
        prep_w1_kernel<<<16, 256, 0, stream>>>(W1, W1p, out, cnt);
        stage1_kernel<<<NT, 256, 0, stream>>>(x, W1p, b1, W2, s_buf, out, cnt);
        spmv_lds_kernel<<<NR * EC, 1024, 0, stream>>>(er, ec, ew, s_buf, P);
        int fb = (NN + 255) / 256;
        finish_lds_kernel<<<fb, 256, 0, stream>>>(P, b2, out, cnt, fb);
    } else {
        // Dense-atomic fallback (needs ~700 KB of ws)
        float*    t    = ws + P_OFF;
        __bf16*   W1pf = (__bf16*)(ws + P_OFF + NN);
        unsigned* cntf = (unsigned*)(ws + P_OFF + NN + DD * KD / 2);
        prep_w1_kernel<<<16, 256, 0, stream>>>(W1, W1pf, out, cntf);
        zero_kernel<<<(NN + 255) / 256, 256, 0, stream>>>(t, out);
        stage1_kernel<<<NT, 256, 0, stream>>>(x, W1pf, b1, W2, s_buf, out, cntf);
        spmv_fallback_kernel<<<(NE / 4 + 255) / 256, 256, 0, stream>>>(er, ec, ew, s_buf, t);
        finish_fallback_kernel<<<(NN + 255) / 256, 256, 0, stream>>>(t, b2, out);
        sqrt_kernel<<<1, 1, 0, stream>>>(out);
    }
}